// Round 11
// baseline (144.811 us; speedup 1.0000x reference)
//
#include <hip/hip_runtime.h>

#define N_NODES 8192
#define E_EDGES 262144
#define EMBDSZ  64
#define NIN     16
#define K_STEPS 4
#define ROWCAP  96    // Poisson(32) realized row max ~56-60 over 8192 rows
#define NBLK    1024  // 4 blocks/CU, co-residency validated in R8/R10
#define NTHR    256

typedef unsigned long long u64;
typedef unsigned u32;
typedef float f32x4 __attribute__((ext_vector_type(4)));

// Relaxed agent-scope (sc1, device-coherent, no cache-maintenance) atomics.
#define AT_LOAD(p)     __hip_atomic_load((p), __ATOMIC_RELAXED, __HIP_MEMORY_SCOPE_AGENT)
#define AT_STORE(p, v) __hip_atomic_store((p), (v), __ATOMIC_RELAXED, __HIP_MEMORY_SCOPE_AGENT)
#define AT_ADD(p, v)   __hip_atomic_fetch_add((p), (v), __ATOMIC_RELAXED, __HIP_MEMORY_SCOPE_AGENT)

// Device-coherent (sc1 write-through) stores; not vmcnt-tracked by the
// compiler, so ordering points use explicit s_waitcnt vmcnt(0).
__device__ __forceinline__ void store_f4_sc1(float* p, f32x4 v) {
    asm volatile("global_store_dwordx4 %0, %1, off sc1" :: "v"(p), "v"(v) : "memory");
}
__device__ __forceinline__ void store_u64_sc1(u64* p, u64 v) {
    asm volatile("global_store_dwordx2 %0, %1, off sc1" :: "v"(p), "v"(v) : "memory");
}
__device__ __forceinline__ void store_f32_sc1(float* p, float v) {
    asm volatile("global_store_dword %0, %1, off sc1" :: "v"(p), "v"(v) : "memory");
}

// D1: zero cursor[8192], prog[8192], done. 32 blocks x 256.
__global__ void init_kernel(u32* __restrict__ cursor, u32* __restrict__ prog,
                            u32* __restrict__ done) {
    int t = blockIdx.x * NTHR + threadIdx.x;   // 0..8191
    cursor[t] = 0;
    prog[t]   = 0;
    if (t == 0) *done = 0;
}

// D2: everything else.
//   embed (2 thr/output, split-K 32+32, sc1 stores)
//   scatter edges -> rowdat {w:32|c:13|eid:18} (1 edge/thread, sc1)
//   [scatter-done counter barrier: the ONLY global sync]
//   stage 2 rows/wave into LDS, dedup in LDS (last-write-wins, kill keeps lo)
//   spmm0 from x0 (ready by barrier), then steps 1-3 by per-row DATAFLOW:
//     poll prog[src] >= k for this row's sources, gather h_{k-1}, store sc1,
//     drain, publish prog[row] = k+1. No grid barriers.
// Coherence: all cross-wave data is sc1 write-through; every consumer
// first-touches a line only after its guard => normal cached gathers are safe.
__global__ void __launch_bounds__(NTHR, 4) mega_kernel(
    const float* __restrict__ nf,
    const float* __restrict__ emb,
    const int*   __restrict__ ei,
    const float* __restrict__ ew,
    float* __restrict__ out,
    float* __restrict__ x0,
    u32*   __restrict__ cursor,
    u64*   __restrict__ rowdat,
    u32*   __restrict__ prog,
    u32*   __restrict__ done)
{
    __shared__ float semb[EMBDSZ * NIN];       // 4 KB
    __shared__ u64   srow[4][2][ROWCAP];       // 6 KB

    const int b = blockIdx.x, tid = threadIdx.x;
    const int wid = tid >> 6, lane = tid & 63;
    const int slane = lane & 15, f4 = lane >> 4;   // 16 edge-slots x 4 f-groups
    const int wave = b * 4 + wid;                  // 4096 waves, 2 rows each
    const int gt = b * NTHR + tid;                 // 0..262143

    // ---- embed: x0 = nf @ Emb ----
    for (int i = tid; i < EMBDSZ * NIN; i += NTHR) semb[i] = emb[i];
    __syncthreads();
    {
        int o = gt >> 1, half = gt & 1;            // output 0..131071
        int n = o >> 4, jj = o & 15;
        const f32x4* nfp = (const f32x4*)(nf + n * EMBDSZ + half * 32);
        const float* ep  = semb + half * 32 * NIN + jj;
        float acc = 0.f;
        #pragma unroll
        for (int k8 = 0; k8 < 8; ++k8) {
            f32x4 a = nfp[k8];
            acc += a.x * ep[(k8 * 4 + 0) * NIN] + a.y * ep[(k8 * 4 + 1) * NIN]
                 + a.z * ep[(k8 * 4 + 2) * NIN] + a.w * ep[(k8 * 4 + 3) * NIN];
        }
        acc += __shfl_xor(acc, 1);
        if (half == 0) store_f32_sc1(&x0[o], acc);
    }
    // ---- scatter: 1 edge per thread ----
    {
        u32 r  = (u32)ei[gt];
        u32 c  = (u32)ei[E_EDGES + gt];
        u32 wb = __float_as_uint(ew[gt]);
        u32 slot = atomicAdd(&cursor[r], 1u);      // IF-homed, no cache allocate
        if (slot < ROWCAP)
            store_u64_sc1(&rowdat[(size_t)r * ROWCAP + slot],
                          ((u64)wb << 32) | (u64)(c << 18) | (u64)(u32)gt);
    }
    // ---- scatter-done barrier (single monotone counter, once per call) ----
    asm volatile("s_waitcnt vmcnt(0)" ::: "memory");   // x0 + rowdat at IF
    __syncthreads();
    if (tid == 0) {
        AT_ADD(done, 1u);
        while (AT_LOAD(done) < (u32)NBLK) __builtin_amdgcn_s_sleep(2);
    }
    __syncthreads();

    // ---- stage rows into LDS + dedup (wave-private slice, in-order LDS) ----
    u32 len[2];
    #pragma unroll
    for (int rr = 0; rr < 2; ++rr) {
        int row = wave * 2 + rr;
        u32 L = min(cursor[row], (u32)ROWCAP);     // first touch post-barrier
        len[rr] = L;
        const u64* rp = rowdat + (size_t)row * ROWCAP;
        for (u32 i = lane; i < L; i += 64) srow[wid][rr][i] = rp[i];
        for (u32 i = lane; i < L; i += 64) {
            u64 v = srow[wid][rr][i];
            u32 lo = (u32)v;
            bool dead = false;
            for (u32 q = 0; q < L; ++q) {
                u32 o = (u32)srow[wid][rr][q];
                dead |= ((o >> 18) == (lo >> 18)) && (o > lo);
            }
            if (dead) srow[wid][rr][i] = (u64)lo;  // weight := 0, keep (c|eid)
        }
    }

    // ---- spmm steps: 0 from x0 (no poll), 1-3 by per-row dataflow ----
    const float* hin = x0;
    for (int k = 0; k < K_STEPS; ++k) {
        float* hout = out + (size_t)k * N_NODES * NIN;
        #pragma unroll
        for (int rr = 0; rr < 2; ++rr) {
            int row = wave * 2 + rr;
            u32 L = len[rr];
            if (k > 0) {                           // wait for my sources
                for (;;) {
                    bool ok = true;
                    for (u32 i = lane; i < L; i += 64) {
                        u32 src = ((u32)srow[wid][rr][i]) >> 18;
                        ok &= (AT_LOAD(&prog[src]) >= (u32)k);
                    }
                    if (__all(ok)) break;
                    __builtin_amdgcn_s_sleep(1);
                }
            }
            f32x4 acc = {0.f, 0.f, 0.f, 0.f};
            for (u32 i = slane; i < L; i += 16) {
                u64 v = srow[wid][rr][i];
                float w = __uint_as_float((u32)(v >> 32));
                u32 c = ((u32)v) >> 18;
                f32x4 h = *(const f32x4*)&hin[c * NIN + f4 * 4];  // first touch
                acc += w * h;
            }
            #pragma unroll
            for (int d = 1; d < 16; d <<= 1) {
                acc.x += __shfl_xor(acc.x, d);
                acc.y += __shfl_xor(acc.y, d);
                acc.z += __shfl_xor(acc.z, d);
                acc.w += __shfl_xor(acc.w, d);
            }
            if (slane == 0) store_f4_sc1(&hout[row * NIN + f4 * 4], acc);
        }
        // publish: h stores acked at IF, then bump both rows' epochs
        asm volatile("s_waitcnt vmcnt(0)" ::: "memory");
        if (lane == 0) {
            AT_STORE(&prog[wave * 2],     (u32)(k + 1));
            AT_STORE(&prog[wave * 2 + 1], (u32)(k + 1));
        }
        hin = hout;
    }
}

extern "C" void kernel_launch(void* const* d_in, const int* in_sizes, int n_in,
                              void* d_out, int out_size, void* d_ws, size_t ws_size,
                              hipStream_t stream) {
    (void)in_sizes; (void)n_in; (void)out_size; (void)ws_size;
    const float* nf  = (const float*)d_in[0];
    const int*   ei  = (const int*)d_in[1];
    const float* ew  = (const float*)d_in[2];
    const float* emb = (const float*)d_in[3];
    float* out = (float*)d_out;

    char* ws = (char*)d_ws;
    size_t off = 0;
    auto alloc = [&](size_t bytes) {
        void* p = ws + off;
        off += (bytes + 255) & ~(size_t)255;
        return p;
    };
    u64*   rowdat = (u64*)alloc((size_t)N_NODES * ROWCAP * 8);   // 6.3 MB
    float* x0     = (float*)alloc((size_t)N_NODES * NIN * 4);    // 512 KB
    u32*   cursor = (u32*)alloc((size_t)N_NODES * 4);            // 32 KB
    u32*   prog   = (u32*)alloc((size_t)N_NODES * 4);            // 32 KB
    u32*   done   = (u32*)alloc(256);

    init_kernel<<<32, NTHR, 0, stream>>>(cursor, prog, done);
    mega_kernel<<<NBLK, NTHR, 0, stream>>>(nf, emb, ei, ew, out, x0,
                                           cursor, rowdat, prog, done);
}

// Round 12
// 60.846 us; speedup vs baseline: 2.3800x; 2.3800x over previous
//
#include <hip/hip_runtime.h>

#define N_NODES 8192
#define E_EDGES 262144
#define EMBDSZ  64
#define NIN     16
#define K_STEPS 4
#define ROWCAP  96    // Poisson(32) realized row max ~56-60 over 8192 rows
#define NTHR    256

typedef unsigned long long u64;
typedef unsigned u32;
typedef float f32x4 __attribute__((ext_vector_type(4)));

// D1: zero row cursors. 4 blocks x 256.
__global__ void init_kernel(u32* __restrict__ cursor) {
    int t = blockIdx.x * NTHR + threadIdx.x;      // 0..1023
    uint4 z = make_uint4(0, 0, 0, 0);
    ((uint4*)cursor)[t * 2]     = z;              // 2048 uint4 = 8192 u32
    ((uint4*)cursor)[t * 2 + 1] = z;
}

// D2: embed (2 threads/output, split-K 32+32, f32x4 nf loads, shfl merge)
// + scatter edges into row buckets {w:32 | c:13 | eid:18}. 1024 blocks x 256.
__global__ void embed_scatter_kernel(const float* __restrict__ nf,
                                     const float* __restrict__ emb,
                                     const int*   __restrict__ ei,
                                     const float* __restrict__ ew,
                                     float* __restrict__ x0,
                                     u32*   __restrict__ cursor,
                                     u64*   __restrict__ rowdat) {
    __shared__ float semb[EMBDSZ * NIN];
    const int b = blockIdx.x, tid = threadIdx.x;
    for (int i = tid; i < EMBDSZ * NIN; i += NTHR) semb[i] = emb[i];
    __syncthreads();
    int gt = b * NTHR + tid;               // 0..262143
    {
        int o = gt >> 1, half = gt & 1;    // output 0..131071
        int n = o >> 4, jj = o & 15;
        const f32x4* nfp = (const f32x4*)(nf + n * EMBDSZ + half * 32);
        const float* ep  = semb + half * 32 * NIN + jj;
        float acc = 0.f;
        #pragma unroll
        for (int k8 = 0; k8 < 8; ++k8) {
            f32x4 a = nfp[k8];
            acc += a.x * ep[(k8 * 4 + 0) * NIN] + a.y * ep[(k8 * 4 + 1) * NIN]
                 + a.z * ep[(k8 * 4 + 2) * NIN] + a.w * ep[(k8 * 4 + 3) * NIN];
        }
        acc += __shfl_xor(acc, 1);
        if (half == 0) x0[o] = acc;
    }
    {
        u32 r  = (u32)ei[gt];              // exactly 1 edge per thread
        u32 c  = (u32)ei[E_EDGES + gt];
        u32 wb = __float_as_uint(ew[gt]);
        u32 slot = atomicAdd(&cursor[r], 1u);
        if (slot < ROWCAP)
            rowdat[(size_t)r * ROWCAP + slot] =
                ((u64)wb << 32) | (u64)(c << 18) | (u64)(u32)gt;
    }
}

// D3: per-row LDS dedup (last-write-wins by max eid) -> compacted {w:32|c:13}
// rows in rowdat2/cursor2, + spmm step 0. 512 blocks, 4 rows/wave (ILP).
__global__ void dedup_spmm0_kernel(const u32* __restrict__ cursor,
                                   const u64* __restrict__ rowdat,
                                   const float* __restrict__ x0,
                                   u64* __restrict__ rowdat2,
                                   u32* __restrict__ cursor2,
                                   float* __restrict__ out) {
    __shared__ u64 srow[4][4][ROWCAP];             // 12 KB
    __shared__ u32 scnt[4][4];
    const int b = blockIdx.x, tid = threadIdx.x;
    const int wid = tid >> 6, lane = tid & 63;
    const int slane = lane & 15, f4 = lane >> 4;   // 16 edge-slots x 4 f-groups
    const int wave = b * 4 + wid;                  // 2048 waves x 4 rows = 8192

    u32 len[4];
    // stage all 4 rows first (independent load streams)
    #pragma unroll
    for (int rr = 0; rr < 4; ++rr) {
        int row = wave * 4 + rr;
        u32 L = min(cursor[row], (u32)ROWCAP);
        len[rr] = L;
        const u64* rp = rowdat + (size_t)row * ROWCAP;
        for (u32 i = lane; i < L; i += 64) srow[wid][rr][i] = rp[i];
        if (lane == rr) scnt[wid][rr] = 0;
    }
    // dedup each row in LDS (wave-private slices, in-order within wave)
    #pragma unroll
    for (int rr = 0; rr < 4; ++rr) {
        int row = wave * 4 + rr;
        u32 L = len[rr];
        for (u32 i = lane; i < L; i += 64) {
            u64 v = srow[wid][rr][i];
            u32 lo = (u32)v;
            bool dead = false;
            for (u32 q = 0; q < L; ++q) {
                u32 o = (u32)srow[wid][rr][q];
                dead |= ((o >> 18) == (lo >> 18)) && (o > lo);
            }
            if (dead) {
                srow[wid][rr][i] = (u64)lo;        // weight := 0, keep (c|eid)
            } else {
                u32 pos = atomicAdd(&scnt[wid][rr], 1u);
                rowdat2[(size_t)row * ROWCAP + pos] =
                    (v & 0xFFFFFFFF00000000ull) | (u64)(lo >> 18); // {w | c}
            }
        }
        if (lane == 0) cursor2[row] = scnt[wid][rr];
    }
    // spmm0: 4 independent accumulator chains per lane
    f32x4 acc[4];
    #pragma unroll
    for (int rr = 0; rr < 4; ++rr) acc[rr] = (f32x4){0.f, 0.f, 0.f, 0.f};
    #pragma unroll
    for (int rr = 0; rr < 4; ++rr) {
        u32 L = len[rr];
        #pragma unroll 2
        for (u32 i = slane; i < L; i += 16) {
            u64 v = srow[wid][rr][i];
            float w = __uint_as_float((u32)(v >> 32));
            u32 c = ((u32)v) >> 18;
            f32x4 h = *(const f32x4*)&x0[c * NIN + f4 * 4];
            acc[rr] += w * h;
        }
    }
    #pragma unroll
    for (int rr = 0; rr < 4; ++rr) {
        #pragma unroll
        for (int d = 1; d < 16; d <<= 1) {
            acc[rr].x += __shfl_xor(acc[rr].x, d);
            acc[rr].y += __shfl_xor(acc[rr].y, d);
            acc[rr].z += __shfl_xor(acc[rr].z, d);
            acc[rr].w += __shfl_xor(acc[rr].w, d);
        }
        if (slane == 0)
            *(f32x4*)&out[(wave * 4 + rr) * NIN + f4 * 4] = acc[rr];
    }
}

// D4-D6: spmm step k. 512 blocks, 4 rows/wave, 16 slots x 4 f-groups.
__global__ void spmm_kernel(const u32* __restrict__ cursor2,
                            const u64* __restrict__ rowdat2,
                            const float* __restrict__ hin,
                            float* __restrict__ hout) {
    const int b = blockIdx.x, tid = threadIdx.x;
    const int wid = tid >> 6, lane = tid & 63;
    const int slane = lane & 15, f4 = lane >> 4;
    const int wave = b * 4 + wid;                  // 2048 waves x 4 rows
    u32 len[4];
    const u64* rp[4];
    #pragma unroll
    for (int rr = 0; rr < 4; ++rr) {
        int row = wave * 4 + rr;
        len[rr] = cursor2[row];
        rp[rr]  = rowdat2 + (size_t)row * ROWCAP;
    }
    f32x4 acc[4];
    #pragma unroll
    for (int rr = 0; rr < 4; ++rr) acc[rr] = (f32x4){0.f, 0.f, 0.f, 0.f};
    #pragma unroll
    for (int rr = 0; rr < 4; ++rr) {
        #pragma unroll 2
        for (u32 i = slane; i < len[rr]; i += 16) {
            u64 v = rp[rr][i];
            float w = __uint_as_float((u32)(v >> 32));
            u32 c = (u32)v & 0x1FFFu;
            f32x4 h = *(const f32x4*)&hin[c * NIN + f4 * 4];
            acc[rr] += w * h;
        }
    }
    #pragma unroll
    for (int rr = 0; rr < 4; ++rr) {
        #pragma unroll
        for (int d = 1; d < 16; d <<= 1) {
            acc[rr].x += __shfl_xor(acc[rr].x, d);
            acc[rr].y += __shfl_xor(acc[rr].y, d);
            acc[rr].z += __shfl_xor(acc[rr].z, d);
            acc[rr].w += __shfl_xor(acc[rr].w, d);
        }
        if (slane == 0)
            *(f32x4*)&hout[(wave * 4 + rr) * NIN + f4 * 4] = acc[rr];
    }
}

extern "C" void kernel_launch(void* const* d_in, const int* in_sizes, int n_in,
                              void* d_out, int out_size, void* d_ws, size_t ws_size,
                              hipStream_t stream) {
    (void)in_sizes; (void)n_in; (void)out_size; (void)ws_size;
    const float* nf  = (const float*)d_in[0];
    const int*   ei  = (const int*)d_in[1];
    const float* ew  = (const float*)d_in[2];
    const float* emb = (const float*)d_in[3];
    float* out = (float*)d_out;

    char* ws = (char*)d_ws;
    size_t off = 0;
    auto alloc = [&](size_t bytes) {
        void* p = ws + off;
        off += (bytes + 255) & ~(size_t)255;
        return p;
    };
    u64*   rowdat  = (u64*)alloc((size_t)N_NODES * ROWCAP * 8);   // 6.3 MB
    u64*   rowdat2 = (u64*)alloc((size_t)N_NODES * ROWCAP * 8);   // 6.3 MB
    float* x0      = (float*)alloc((size_t)N_NODES * NIN * 4);    // 512 KB
    u32*   cursor  = (u32*)alloc((size_t)N_NODES * 4);            // 32 KB
    u32*   cursor2 = (u32*)alloc((size_t)N_NODES * 4);            // 32 KB

    init_kernel<<<4, NTHR, 0, stream>>>(cursor);
    embed_scatter_kernel<<<1024, NTHR, 0, stream>>>(nf, emb, ei, ew, x0, cursor, rowdat);
    dedup_spmm0_kernel<<<512, NTHR, 0, stream>>>(cursor, rowdat, x0, rowdat2, cursor2, out);
    const float* hin = out;
    for (int k = 1; k < K_STEPS; ++k) {
        float* hout = out + (size_t)k * N_NODES * NIN;
        spmm_kernel<<<512, NTHR, 0, stream>>>(cursor2, rowdat2, hin, hout);
        hin = hout;
    }
}

// Round 13
// 47.452 us; speedup vs baseline: 3.0518x; 1.2823x over previous
//
#include <hip/hip_runtime.h>

#define N_NODES 8192
#define E_EDGES 262144
#define EMBDSZ  64
#define NIN     16
#define K_STEPS 4
#define ROWCAP  96    // Poisson(32) realized row max ~56-60 over 8192 rows
#define NTHR    256

typedef unsigned long long u64;
typedef unsigned u32;
typedef float f32x4 __attribute__((ext_vector_type(4)));

// D1: zero row cursors. 8 blocks x 256.
__global__ void init_kernel(u32* __restrict__ cursor) {
    int t = blockIdx.x * NTHR + threadIdx.x;      // 0..2047
    ((uint4*)cursor)[t] = make_uint4(0, 0, 0, 0); // 2048 uint4 = 8192 u32
}

// D2: scatter edges into row buckets {w:32|c:13|eid:18} (1 edge/thread,
// issued FIRST so the IF-latency chain retires under embed's FMAs)
// + embed (2 threads/output, split-K 32+32, f32x4 nf loads, shfl merge).
__global__ void embed_scatter_kernel(const float* __restrict__ nf,
                                     const float* __restrict__ emb,
                                     const int*   __restrict__ ei,
                                     const float* __restrict__ ew,
                                     float* __restrict__ x0,
                                     u32*   __restrict__ cursor,
                                     u64*   __restrict__ rowdat) {
    __shared__ float semb[EMBDSZ * NIN];
    const int b = blockIdx.x, tid = threadIdx.x;
    const int gt = b * NTHR + tid;         // 0..262143
    // scatter first: independent of LDS/embed
    {
        u32 r  = (u32)ei[gt];
        u32 c  = (u32)ei[E_EDGES + gt];
        u32 wb = __float_as_uint(ew[gt]);
        u32 slot = atomicAdd(&cursor[r], 1u);
        if (slot < ROWCAP)
            rowdat[(size_t)r * ROWCAP + slot] =
                ((u64)wb << 32) | (u64)(c << 18) | (u64)(u32)gt;
    }
    for (int i = tid; i < EMBDSZ * NIN; i += NTHR) semb[i] = emb[i];
    __syncthreads();
    {
        int o = gt >> 1, half = gt & 1;    // output 0..131071
        int n = o >> 4, jj = o & 15;
        const f32x4* nfp = (const f32x4*)(nf + n * EMBDSZ + half * 32);
        const float* ep  = semb + half * 32 * NIN + jj;
        float acc = 0.f;
        #pragma unroll
        for (int k8 = 0; k8 < 8; ++k8) {
            f32x4 a = nfp[k8];
            acc += a.x * ep[(k8 * 4 + 0) * NIN] + a.y * ep[(k8 * 4 + 1) * NIN]
                 + a.z * ep[(k8 * 4 + 2) * NIN] + a.w * ep[(k8 * 4 + 3) * NIN];
        }
        acc += __shfl_xor(acc, 1);
        if (half == 0) x0[o] = acc;
    }
}

// D3: per-row LDS dedup (last-write-wins by max eid) -> compacted {w:32|c:13}
// rows in rowdat2/cursor2, + spmm step 0. 2048 blocks, 1 ROW PER WAVE.
__global__ void dedup_spmm0_kernel(const u32* __restrict__ cursor,
                                   const u64* __restrict__ rowdat,
                                   const float* __restrict__ x0,
                                   u64* __restrict__ rowdat2,
                                   u32* __restrict__ cursor2,
                                   float* __restrict__ out) {
    __shared__ u32   slo[4][ROWCAP];
    __shared__ float swt[4][ROWCAP];
    __shared__ u32   scnt[4];
    const int b = blockIdx.x, tid = threadIdx.x;
    const int wid = tid >> 6, lane = tid & 63;
    const int slane = lane & 15, f4 = lane >> 4;   // 16 edge-slots x 4 f-groups
    const int row = b * 4 + wid;                   // 8192 waves == 8192 rows

    u32 len = min(cursor[row], (u32)ROWCAP);
    size_t base = (size_t)row * ROWCAP;
    if (lane == 0) scnt[wid] = 0;
    for (u32 i = lane; i < len; i += 64) {
        u64 v = rowdat[base + i];
        slo[wid][i] = (u32)v;                          // (c<<18)|eid
        swt[wid][i] = __uint_as_float((u32)(v >> 32));
    }
    // wave-private LDS slice: same-wave LDS ops are in-order, no syncthreads
    for (u32 i = lane; i < len; i += 64) {
        u32 lo = slo[wid][i];
        bool dead = false;
        for (u32 q = 0; q < len; ++q) {
            u32 o = slo[wid][q];
            dead |= ((o >> 18) == (lo >> 18)) && (o > lo);
        }
        if (dead) {
            swt[wid][i] = 0.f;
        } else {
            u32 pos = atomicAdd(&scnt[wid], 1u);       // LDS atomic
            rowdat2[base + pos] =
                ((u64)(u32)__float_as_uint(swt[wid][i]) << 32) |
                (u64)(lo >> 18);                       // {w:32 | c:13}
        }
    }
    if (lane == 0) cursor2[row] = scnt[wid];
    // spmm0: LDS weights (dups zeroed) x x0 gather
    f32x4 acc = {0.f, 0.f, 0.f, 0.f};
    for (u32 i = slane; i < len; i += 16) {
        float w = swt[wid][i];
        u32 c = slo[wid][i] >> 18;
        f32x4 h = *(const f32x4*)&x0[c * NIN + f4 * 4];
        acc += w * h;
    }
    #pragma unroll
    for (int d = 1; d < 16; d <<= 1) {
        acc.x += __shfl_xor(acc.x, d);
        acc.y += __shfl_xor(acc.y, d);
        acc.z += __shfl_xor(acc.z, d);
        acc.w += __shfl_xor(acc.w, d);
    }
    if (slane == 0) *(f32x4*)&out[row * NIN + f4 * 4] = acc;
}

// D4-D6: spmm step k from compacted rows. 2048 blocks, 1 ROW PER WAVE.
__global__ void spmm_kernel(const u32* __restrict__ cursor2,
                            const u64* __restrict__ rowdat2,
                            const float* __restrict__ hin,
                            float* __restrict__ hout) {
    const int b = blockIdx.x, tid = threadIdx.x;
    const int wid = tid >> 6, lane = tid & 63;
    const int slane = lane & 15, f4 = lane >> 4;
    const int row = b * 4 + wid;                   // 8192 waves == 8192 rows
    u32 len = cursor2[row];
    const u64* rp = rowdat2 + (size_t)row * ROWCAP;
    f32x4 acc = {0.f, 0.f, 0.f, 0.f};
    #pragma unroll 2
    for (u32 i = slane; i < len; i += 16) {
        u64 v = rp[i];
        float w = __uint_as_float((u32)(v >> 32));
        u32 c = (u32)v & 0x1FFFu;
        f32x4 h = *(const f32x4*)&hin[c * NIN + f4 * 4];
        acc += w * h;
    }
    #pragma unroll
    for (int d = 1; d < 16; d <<= 1) {
        acc.x += __shfl_xor(acc.x, d);
        acc.y += __shfl_xor(acc.y, d);
        acc.z += __shfl_xor(acc.z, d);
        acc.w += __shfl_xor(acc.w, d);
    }
    if (slane == 0) *(f32x4*)&hout[row * NIN + f4 * 4] = acc;
}

extern "C" void kernel_launch(void* const* d_in, const int* in_sizes, int n_in,
                              void* d_out, int out_size, void* d_ws, size_t ws_size,
                              hipStream_t stream) {
    (void)in_sizes; (void)n_in; (void)out_size; (void)ws_size;
    const float* nf  = (const float*)d_in[0];
    const int*   ei  = (const int*)d_in[1];
    const float* ew  = (const float*)d_in[2];
    const float* emb = (const float*)d_in[3];
    float* out = (float*)d_out;

    char* ws = (char*)d_ws;
    size_t off = 0;
    auto alloc = [&](size_t bytes) {
        void* p = ws + off;
        off += (bytes + 255) & ~(size_t)255;
        return p;
    };
    u64*   rowdat  = (u64*)alloc((size_t)N_NODES * ROWCAP * 8);   // 6.3 MB
    u64*   rowdat2 = (u64*)alloc((size_t)N_NODES * ROWCAP * 8);   // 6.3 MB
    float* x0      = (float*)alloc((size_t)N_NODES * NIN * 4);    // 512 KB
    u32*   cursor  = (u32*)alloc((size_t)N_NODES * 4);            // 32 KB
    u32*   cursor2 = (u32*)alloc((size_t)N_NODES * 4);            // 32 KB

    init_kernel<<<8, NTHR, 0, stream>>>(cursor);
    embed_scatter_kernel<<<1024, NTHR, 0, stream>>>(nf, emb, ei, ew, x0, cursor, rowdat);
    dedup_spmm0_kernel<<<2048, NTHR, 0, stream>>>(cursor, rowdat, x0, rowdat2, cursor2, out);
    const float* hin = out;
    for (int k = 1; k < K_STEPS; ++k) {
        float* hout = out + (size_t)k * N_NODES * NIN;
        spmm_kernel<<<2048, NTHR, 0, stream>>>(cursor2, rowdat2, hin, hout);
        hin = hout;
    }
}

// Round 14
// 47.190 us; speedup vs baseline: 3.0687x; 1.0055x over previous
//
#include <hip/hip_runtime.h>

#define N_NODES 8192
#define E_EDGES 262144
#define EMBDSZ  64
#define NIN     16
#define K_STEPS 4
#define ROWCAP  96    // Poisson(32) realized row max ~56-60 over 8192 rows
#define NTHR    256

typedef unsigned long long u64;
typedef unsigned u32;
typedef float f32x4 __attribute__((ext_vector_type(4)));

// D1: zero row cursors. 8 blocks x 256.
__global__ void init_kernel(u32* __restrict__ cursor) {
    int t = blockIdx.x * NTHR + threadIdx.x;      // 0..2047
    ((uint4*)cursor)[t] = make_uint4(0, 0, 0, 0); // 2048 uint4 = 8192 u32
}

// D2: scatter edges into row buckets {w:32|c:13|eid:18} (1 edge/thread,
// issued FIRST so the IF-latency chain retires under embed's FMAs)
// + embed (2 threads/output, split-K 32+32, f32x4 loads, shfl merge).
__global__ void embed_scatter_kernel(const float* __restrict__ nf,
                                     const float* __restrict__ emb,
                                     const int*   __restrict__ ei,
                                     const float* __restrict__ ew,
                                     float* __restrict__ x0,
                                     u32*   __restrict__ cursor,
                                     u64*   __restrict__ rowdat) {
    __shared__ float semb[EMBDSZ * NIN];
    const int b = blockIdx.x, tid = threadIdx.x;
    const int gt = b * NTHR + tid;         // 0..262143
    // scatter first: independent of LDS/embed
    {
        u32 r  = (u32)ei[gt];
        u32 c  = (u32)ei[E_EDGES + gt];
        u32 wb = __float_as_uint(ew[gt]);
        u32 slot = atomicAdd(&cursor[r], 1u);
        if (slot < ROWCAP)
            rowdat[(size_t)r * ROWCAP + slot] =
                ((u64)wb << 32) | (u64)(c << 18) | (u64)(u32)gt;
    }
    // stage Emb: 256 threads x one f32x4 = 4 KB
    ((f32x4*)semb)[tid] = ((const f32x4*)emb)[tid];
    __syncthreads();
    {
        int o = gt >> 1, half = gt & 1;    // output 0..131071
        int n = o >> 4, jj = o & 15;
        const f32x4* nfp = (const f32x4*)(nf + n * EMBDSZ + half * 32);
        const float* ep  = semb + half * 32 * NIN + jj;
        float acc = 0.f;
        #pragma unroll
        for (int k8 = 0; k8 < 8; ++k8) {
            f32x4 a = nfp[k8];
            acc += a.x * ep[(k8 * 4 + 0) * NIN] + a.y * ep[(k8 * 4 + 1) * NIN]
                 + a.z * ep[(k8 * 4 + 2) * NIN] + a.w * ep[(k8 * 4 + 3) * NIN];
        }
        acc += __shfl_xor(acc, 1);
        if (half == 0) x0[o] = acc;
    }
}

// D3: per-row LDS dedup (last-write-wins by max eid) -> compacted {w:32|c:13}
// rows in rowdat2/cursor2, + spmm step 0. 2048 blocks, 1 ROW PER WAVE.
__global__ void dedup_spmm0_kernel(const u32* __restrict__ cursor,
                                   const u64* __restrict__ rowdat,
                                   const float* __restrict__ x0,
                                   u64* __restrict__ rowdat2,
                                   u32* __restrict__ cursor2,
                                   float* __restrict__ out) {
    __shared__ u32   slo[4][ROWCAP];
    __shared__ float swt[4][ROWCAP];
    __shared__ u32   scnt[4];
    const int b = blockIdx.x, tid = threadIdx.x;
    const int wid = tid >> 6, lane = tid & 63;
    const int slane = lane & 15, f4 = lane >> 4;   // 16 edge-slots x 4 f-groups
    const int row = b * 4 + wid;                   // 8192 waves == 8192 rows

    u32 len = min(cursor[row], (u32)ROWCAP);
    size_t base = (size_t)row * ROWCAP;
    if (lane == 0) scnt[wid] = 0;
    for (u32 i = lane; i < len; i += 64) {
        u64 v = rowdat[base + i];
        slo[wid][i] = (u32)v;                          // (c<<18)|eid
        swt[wid][i] = __uint_as_float((u32)(v >> 32));
    }
    // wave-private LDS slice: same-wave LDS ops are in-order, no syncthreads
    for (u32 i = lane; i < len; i += 64) {
        u32 lo = slo[wid][i];
        bool dead = false;
        for (u32 q = 0; q < len; ++q) {
            u32 o = slo[wid][q];
            dead |= ((o >> 18) == (lo >> 18)) && (o > lo);
        }
        if (dead) {
            swt[wid][i] = 0.f;
        } else {
            u32 pos = atomicAdd(&scnt[wid], 1u);       // LDS atomic
            rowdat2[base + pos] =
                ((u64)(u32)__float_as_uint(swt[wid][i]) << 32) |
                (u64)(lo >> 18);                       // {w:32 | c:13}
        }
    }
    if (lane == 0) cursor2[row] = scnt[wid];
    // spmm0: LDS weights (dups zeroed) x x0 gather
    f32x4 acc = {0.f, 0.f, 0.f, 0.f};
    #pragma unroll 2
    for (u32 i = slane; i < len; i += 16) {
        float w = swt[wid][i];
        u32 c = slo[wid][i] >> 18;
        f32x4 h = *(const f32x4*)&x0[c * NIN + f4 * 4];
        acc += w * h;
    }
    #pragma unroll
    for (int d = 1; d < 16; d <<= 1) {
        acc.x += __shfl_xor(acc.x, d);
        acc.y += __shfl_xor(acc.y, d);
        acc.z += __shfl_xor(acc.z, d);
        acc.w += __shfl_xor(acc.w, d);
    }
    if (slane == 0) *(f32x4*)&out[row * NIN + f4 * 4] = acc;
}

// D4-D6: spmm step k from compacted rows. 2048 blocks, 1 ROW PER WAVE.
__global__ void spmm_kernel(const u32* __restrict__ cursor2,
                            const u64* __restrict__ rowdat2,
                            const float* __restrict__ hin,
                            float* __restrict__ hout) {
    const int b = blockIdx.x, tid = threadIdx.x;
    const int wid = tid >> 6, lane = tid & 63;
    const int slane = lane & 15, f4 = lane >> 4;
    const int row = b * 4 + wid;                   // 8192 waves == 8192 rows
    const u32 len = cursor2[row];
    const u64* rp = rowdat2 + (size_t)row * ROWCAP;
    f32x4 acc = {0.f, 0.f, 0.f, 0.f};
    #pragma unroll 2
    for (u32 i = slane; i < len; i += 16) {
        u64 v = rp[i];
        float w = __uint_as_float((u32)(v >> 32));
        u32 c = (u32)v & 0x1FFFu;
        f32x4 h = *(const f32x4*)&hin[c * NIN + f4 * 4];
        acc += w * h;
    }
    #pragma unroll
    for (int d = 1; d < 16; d <<= 1) {
        acc.x += __shfl_xor(acc.x, d);
        acc.y += __shfl_xor(acc.y, d);
        acc.z += __shfl_xor(acc.z, d);
        acc.w += __shfl_xor(acc.w, d);
    }
    if (slane == 0) *(f32x4*)&hout[row * NIN + f4 * 4] = acc;
}

extern "C" void kernel_launch(void* const* d_in, const int* in_sizes, int n_in,
                              void* d_out, int out_size, void* d_ws, size_t ws_size,
                              hipStream_t stream) {
    (void)in_sizes; (void)n_in; (void)out_size; (void)ws_size;
    const float* nf  = (const float*)d_in[0];
    const int*   ei  = (const int*)d_in[1];
    const float* ew  = (const float*)d_in[2];
    const float* emb = (const float*)d_in[3];
    float* out = (float*)d_out;

    char* ws = (char*)d_ws;
    size_t off = 0;
    auto alloc = [&](size_t bytes) {
        void* p = ws + off;
        off += (bytes + 255) & ~(size_t)255;
        return p;
    };
    u64*   rowdat  = (u64*)alloc((size_t)N_NODES * ROWCAP * 8);   // 6.3 MB
    u64*   rowdat2 = (u64*)alloc((size_t)N_NODES * ROWCAP * 8);   // 6.3 MB
    float* x0      = (float*)alloc((size_t)N_NODES * NIN * 4);    // 512 KB
    u32*   cursor  = (u32*)alloc((size_t)N_NODES * 4);            // 32 KB
    u32*   cursor2 = (u32*)alloc((size_t)N_NODES * 4);            // 32 KB

    init_kernel<<<8, NTHR, 0, stream>>>(cursor);
    embed_scatter_kernel<<<1024, NTHR, 0, stream>>>(nf, emb, ei, ew, x0, cursor, rowdat);
    dedup_spmm0_kernel<<<2048, NTHR, 0, stream>>>(cursor, rowdat, x0, rowdat2, cursor2, out);
    const float* hin = out;
    for (int k = 1; k < K_STEPS; ++k) {
        float* hout = out + (size_t)k * N_NODES * NIN;
        spmm_kernel<<<2048, NTHR, 0, stream>>>(cursor2, rowdat2, hin, hout);
        hin = hout;
    }
}